// Round 12
// baseline (99.123 us; speedup 1.0000x reference)
//
#include <hip/hip_runtime.h>
#include <stdint.h>

// SparseConv3d bf16-MFMA implicit GEMM. B=2, Cin=32, Cout=64, D=64, K=3.
// Round 12: 4y-per-wave + pipelined weights, on r11's conflict-free oct layout.
//   Block = 256 thr / 4 waves (ct x xtile); wave = 4y x 32x x 32co.
//   Per phase (zr,cb): 18 ds_read_b128 : 36 MFMA (ratio 2, was 1.5) and each
//   wf frag used 4x (weight L1 traffic halved). wf for phase p+1 prefetched
//   during phase p's MFMA burst (wfA/wfB ping-pong, static indexing).
//   LDS = [zr3][oct4][row6][sx66]x16B = 76KB, 2 blocks/CU.
// xt: [b][z][oct][yy(66 pad)][sx(66 pad)] 16B units; zero pad rows/slots.

#define DD 64
#define CIN 32
#define COUT 64

typedef __bf16 bf16x8 __attribute__((ext_vector_type(8)));
typedef float f32x16 __attribute__((ext_vector_type(16)));

#define ROW_B_    1056u                                 // 66 sx * 16B
#define OCT_B     6336u                                 // 6 rows * 1056
#define SLAB_B    25344u                                // 4 octs (one z-plane)
#define PLANE_OCT (66u * ROW_B_)                        // one oct, full plane
#define XT_BYTES  ((size_t)2 * 64 * 4 * 66 * ROW_B_)    // 35,684,352
#define WPK_U16   (27 * 2 * 2 * 64 * 8)                 // 55,296
#define WPK_BYTES ((size_t)WPK_U16 * 2)
#define ZP_BYTES  ((size_t)SLAB_B)
#define WS_NEEDED (XT_BYTES + WPK_BYTES + ZP_BYTES)
#define CONV_LDS  (3 * 25344)                           // 76,032 B

__device__ __forceinline__ uint16_t f2bf(float f) {
    uint32_t u = __builtin_bit_cast(uint32_t, f);
    u += 0x7fffu + ((u >> 16) & 1u);   // RNE
    return (uint16_t)(u >> 16);
}

__device__ __forceinline__ void gll16(const void* g, void* l) {
    __builtin_amdgcn_global_load_lds(
        (__attribute__((address_space(1))) void*)g,
        (__attribute__((address_space(3))) void*)l, 16, 0, 0);
}

// ---------------- pre-kernel 1: weight pack + zero slab ----------------
// wpk flat: (((k27*2 + cb)*2 + ct)*64 + lane)*8 + j
//   lane holds A[co = ct*32 + (lane&31)][ci = cb*16 + (lane>>5)*8 + j]
__global__ void pack_weights(const float* __restrict__ w, uint16_t* __restrict__ wpk,
                             uint4* __restrict__ zp) {
    int flat = blockIdx.x * 256 + threadIdx.x;
    if (flat < WPK_U16) {
        int j   = flat & 7;
        int l   = (flat >> 3) & 63;
        int ct  = (flat >> 9) & 1;
        int cb  = (flat >> 10) & 1;
        int k27 = flat >> 11;
        int co = ct * 32 + (l & 31);
        int ci = cb * 16 + ((l >> 5) * 8) + j;
        wpk[flat] = f2bf(w[(co * CIN + ci) * 27 + k27]);
    } else if (flat - WPK_U16 < (int)(ZP_BYTES / 16)) {
        zp[flat - WPK_U16] = make_uint4(0, 0, 0, 0);
    }
}

// ---------------- pre-kernel 2: x -> oct-major padded channel-last bf16 ----------------
__global__ __launch_bounds__(256)
void transpose_x(const float* __restrict__ x, uint16_t* __restrict__ xt) {
    __shared__ uint16_t tile[4 * 66 * 8];   // [oct][sx][j]
    const int yy = blockIdx.x, z = blockIdx.y, b = blockIdx.z;
    const int y = yy - 1;
    const int t = threadIdx.x;
    uint4* dst0 = (uint4*)(xt + ((((size_t)(b * DD + z)) * 4 + 0) * 66 + yy) * (ROW_B_ / 2));
    const size_t oct_stride4 = PLANE_OCT / 16;

    if (y < 0 || y >= DD) {
        for (int i = t; i < 264; i += 256)
            dst0[(i / 66) * oct_stride4 + (i % 66)] = make_uint4(0, 0, 0, 0);
        return;
    }
    const int ci = t >> 3;
    const int xs = (t & 7) * 8;
    const float* src = x + ((((size_t)b * CIN + ci) * DD + z) * DD + y) * DD + xs;
    float4 v0 = *(const float4*)src;
    float4 v1 = *(const float4*)(src + 4);
    float vals[8] = {v0.x, v0.y, v0.z, v0.w, v1.x, v1.y, v1.z, v1.w};
    const int oct = ci >> 3, j = ci & 7;
#pragma unroll
    for (int e = 0; e < 8; ++e)
        tile[(oct * 66 + (xs + e + 1)) * 8 + j] = f2bf(vals[e]);
    if (t < 64) {
        const int o2 = t >> 4, s2 = ((t >> 3) & 1) ? 65 : 0, j2 = t & 7;
        tile[(o2 * 66 + s2) * 8 + j2] = 0;
    }
    __syncthreads();
    const uint4* t4 = (const uint4*)tile;
    for (int i = t; i < 264; i += 256)
        dst0[(i / 66) * oct_stride4 + (i % 66)] = t4[i];
}

// ---------------- main kernel ----------------
// grid (16 yq, 64 z, 2 b) x 256 thr = 4 waves: ct = w&1, xtile = w>>1.
// Wave: 4y x 32x x 32co. Phases (zr,cb): 9 wf (prefetched) : 18 ds : 36 MFMA.
__global__ __launch_bounds__(256, 2)
void conv_mfma(const uint16_t* __restrict__ xt, const uint16_t* __restrict__ wpk,
               const uint16_t* __restrict__ zp,
               const int* __restrict__ mask, const float* __restrict__ bias,
               float* __restrict__ out) {
    extern __shared__ __align__(16) unsigned char lds[];   // [zr3][oct4][row6][sx66]x16B
    const int yq = blockIdx.x, z = blockIdx.y, b = blockIdx.z;
    const int y0 = yq * 4;
    const int tid = threadIdx.x;
    const int lane = tid & 63;
    const int w = __builtin_amdgcn_readfirstlane(tid >> 6);
    const int ct    = w & 1;
    const int xtile = w >> 1;
    const int u = lane & 31;
    const int h = lane >> 5;
    const int xoff = xtile * 32;

    // ---- stage 12 runs (zr x oct), 6336 B contiguous each; OOB z -> zero slab ----
    for (int r = w; r < 12; r += 4) {
        const int zr = r >> 2, oct = r & 3;
        const int zz = z - 1 + zr;
        const char* g = (zz >= 0 && zz < DD)
            ? (const char*)xt + ((((size_t)(b * DD + zz)) * 4 + oct) * 66 + y0) * ROW_B_
            : (const char*)zp + oct * OCT_B;
        const unsigned l = (unsigned)(zr * SLAB_B + oct * OCT_B);
#pragma unroll
        for (int c = 0; c < 6; ++c)
            gll16(g + c * 1024 + lane * 16, &lds[l + (unsigned)c * 1024u]);
        if (lane < 12) gll16(g + 6144 + lane * 16, &lds[l + 6144u]);
    }

    bf16x8 wfA[9], wfB[9];
#define LOAD_WF(DST, zr_, cb_)                                                     \
    _Pragma("unroll") for (int q = 0; q < 9; ++q)                                  \
        DST[q] = *(const bf16x8*)(wpk                                              \
            + (size_t)((((zr_) * 9 + q) * 2 + (cb_)) * 2 + ct) * 512 + lane * 8);

    LOAD_WF(wfA, 0, 0)          // phase-0 weights in flight during barrier wait
    __syncthreads();

    f32x16 acc[4] = {};         // y = y0 .. y0+3

#define PHASE(zr_, cb_, WFC, WFN, pzr, pcb, DOPRE)                                 \
    {   const unsigned ob = (unsigned)((zr_) * SLAB_B + ((cb_) * 2 + h) * OCT_B)   \
                          + (unsigned)(xoff + u) * 16u;                            \
        if (DOPRE) { LOAD_WF(WFN, pzr, pcb) }                                      \
        _Pragma("unroll") for (int t = 0; t < 6; ++t) {                            \
            bf16x8 bf[3];                                                          \
            _Pragma("unroll") for (int kx = 0; kx < 3; ++kx)                       \
                bf[kx] = *(const bf16x8*)&lds[ob + (unsigned)t * ROW_B_ + kx * 16u];\
            _Pragma("unroll") for (int ly = 0; ly < 4; ++ly) {                     \
                const int ky = t - ly;                                             \
                if (ky >= 0 && ky < 3) {                                           \
                    _Pragma("unroll") for (int kx = 0; kx < 3; ++kx)               \
                        acc[ly] = __builtin_amdgcn_mfma_f32_32x32x16_bf16(         \
                            WFC[ky * 3 + kx], bf[kx], acc[ly], 0, 0, 0);           \
                }                                                                  \
            }                                                                      \
        }                                                                          \
    }

    PHASE(0, 0, wfA, wfB, 0, 1, 1)
    PHASE(0, 1, wfB, wfA, 1, 0, 1)
    PHASE(1, 0, wfA, wfB, 1, 1, 1)
    PHASE(1, 1, wfB, wfA, 2, 0, 1)
    PHASE(2, 0, wfA, wfB, 2, 1, 1)
    PHASE(2, 1, wfB, wfA, 0, 0, 0)
#undef PHASE
#undef LOAD_WF

    // ---- epilogue: +bias, x mask, store. C: col = u (x), row = (r&3)+8*(r>>2)+4*h (co) ----
    const size_t mb = (((size_t)b * DD + z) * DD + y0) * DD + xoff + u;
    float m[4];
#pragma unroll
    for (int ly = 0; ly < 4; ++ly) m[ly] = mask[mb + ly * DD] ? 1.0f : 0.0f;
#pragma unroll
    for (int r = 0; r < 16; ++r) {
        const int co = ct * 32 + (r & 3) + 8 * (r >> 2) + 4 * h;
        const float bs = bias[co];
        const size_t o = (((size_t)(b * COUT + co) * DD + z) * DD + y0) * DD + xoff + u;
#pragma unroll
        for (int ly = 0; ly < 4; ++ly)
            out[o + ly * DD] = (acc[ly][r] + bs) * m[ly];
    }
}

// ---------------- fp32 fallback (ws too small) ----------------
#define CI_BLK 16
__global__ __launch_bounds__(256, 2)
void sparse_conv3d_f32(const float* __restrict__ x,
                       const int* __restrict__ mask,
                       const float* __restrict__ weight,
                       const float* __restrict__ bias,
                       float* __restrict__ out) {
    __shared__ float lds[9 * CI_BLK * 66];
    const int y = blockIdx.x, z = blockIdx.y, b = blockIdx.z;
    const int lane = threadIdx.x & 63;
    const int wave = __builtin_amdgcn_readfirstlane(threadIdx.x >> 6);
    float acc[16];
#pragma unroll
    for (int j = 0; j < 16; ++j) acc[j] = 0.0f;
    const int co0 = wave * 16;
    const float* wbase = weight + (size_t)co0 * (CIN * 27);
    for (int cbl = 0; cbl < 2; ++cbl) {
        if (cbl) __syncthreads();
        for (int i = wave; i < 9 * CI_BLK; i += 4) {
            const int r = i >> 4, ci_l = i & 15;
            const int zz = z + (r / 3) - 1, yy = y + (r % 3) - 1;
            const int ci = cbl * CI_BLK + ci_l;
            float v = 0.0f;
            if (zz >= 0 && zz < DD && yy >= 0 && yy < DD)
                v = x[((((size_t)b * CIN + ci) * DD + zz) * DD + yy) * DD + lane];
            float* row = &lds[(size_t)i * 66];
            row[1 + lane] = v;
            if (lane == 0) { row[0] = 0.0f; row[65] = 0.0f; }
        }
        __syncthreads();
        for (int ci_l = 0; ci_l < CI_BLK; ++ci_l) {
            const int ci = cbl * CI_BLK + ci_l;
#pragma unroll
            for (int kz = 0; kz < 3; ++kz) {
#pragma unroll
                for (int ky = 0; ky < 3; ++ky) {
                    const int r = kz * 3 + ky;
                    const float* xrow = &lds[(size_t)(r * CI_BLK + ci_l) * 66 + lane];
                    const float xv0 = xrow[0], xv1 = xrow[1], xv2 = xrow[2];
                    const float* wp = wbase + ci * 27 + kz * 9 + ky * 3;
#pragma unroll
                    for (int j = 0; j < 16; ++j) {
                        acc[j] += wp[(size_t)j * (CIN * 27) + 0] * xv0
                                + wp[(size_t)j * (CIN * 27) + 1] * xv1
                                + wp[(size_t)j * (CIN * 27) + 2] * xv2;
                    }
                }
            }
        }
    }
    const float m = mask[(((size_t)b * DD + z) * DD + y) * DD + lane] ? 1.0f : 0.0f;
#pragma unroll
    for (int j = 0; j < 16; ++j) {
        const int co = co0 + j;
        out[((((size_t)b * COUT + co) * DD + z) * DD + y) * DD + lane] = (acc[j] + bias[co]) * m;
    }
}
#undef CI_BLK

extern "C" void kernel_launch(void* const* d_in, const int* in_sizes, int n_in,
                              void* d_out, int out_size, void* d_ws, size_t ws_size,
                              hipStream_t stream) {
    const float* x    = (const float*)d_in[0];
    const int*   mask = (const int*)d_in[1];
    const float* w    = (const float*)d_in[2];
    const float* bias = (const float*)d_in[3];
    float*       out  = (float*)d_out;

    if (ws_size < WS_NEEDED) {
        sparse_conv3d_f32<<<dim3(DD, DD, 2), 256, 0, stream>>>(x, mask, w, bias, out);
        return;
    }

    uint16_t* xt  = (uint16_t*)d_ws;
    uint16_t* wpk = (uint16_t*)((char*)d_ws + XT_BYTES);
    uint16_t* zp  = (uint16_t*)((char*)d_ws + XT_BYTES + WPK_BYTES);

    pack_weights<<<(WPK_U16 + (int)(ZP_BYTES / 16) + 255) / 256, 256, 0, stream>>>(w, wpk, (uint4*)zp);
    transpose_x<<<dim3(66, DD, 2), 256, 0, stream>>>(x, xt);
    conv_mfma<<<dim3(16, DD, 2), 256, CONV_LDS, stream>>>(xt, wpk, zp, mask, bias, out);
}

// Round 13
// 94.912 us; speedup vs baseline: 1.0444x; 1.0444x over previous
//
#include <hip/hip_runtime.h>
#include <stdint.h>

// SparseConv3d bf16-MFMA implicit GEMM. B=2, Cin=32, Cout=64, D=64, K=3.
// Round 13: r12 per-wave economy (wave = 4y x 32x x 32co; 18 ds : 36 MFMA per
//   phase; 4x wf reuse) at 2x the occupancy via 2-oct LDS two-pass:
//   LDS = [zr3][oct2][row6][sx66]x16B = 38KB -> 4 blocks/CU = 16 waves/CU.
//   Pass cb: stage octs {2cb, 2cb+1} (38KB), barrier, 3 phases (zr=0..2),
//   barrier, restage. Total staged bytes unchanged (76KB/block) -> FETCH ~28MB.
//   No wf ping-pong (register lean, <=128 VGPR for 4 waves/SIMD).
// xt: [b][z][oct][yy(66 pad)][sx(66 pad)] 16B units; zero pad rows/slots
//   (conflict-free oct-major layout from r11; SQ_LDS_BANK_CONFLICT = 0).

#define DD 64
#define CIN 32
#define COUT 64

typedef __bf16 bf16x8 __attribute__((ext_vector_type(8)));
typedef float f32x16 __attribute__((ext_vector_type(16)));

#define ROW_B_    1056u                                 // 66 sx * 16B
#define OCT_B     6336u                                 // 6 rows * 1056
#define SLAB2_B   12672u                                // 2 octs (one cb, one z-plane)
#define PLANE_OCT (66u * ROW_B_)                        // one oct, full plane
#define XT_BYTES  ((size_t)2 * 64 * 4 * 66 * ROW_B_)    // 35,684,352
#define WPK_U16   (27 * 2 * 2 * 64 * 8)                 // 55,296
#define WPK_BYTES ((size_t)WPK_U16 * 2)
#define ZP_BYTES  ((size_t)(4u * OCT_B))                // zero slab (4 octs)
#define WS_NEEDED (XT_BYTES + WPK_BYTES + ZP_BYTES)
#define CONV_LDS  (3 * 12672)                           // 38,016 B

__device__ __forceinline__ uint16_t f2bf(float f) {
    uint32_t u = __builtin_bit_cast(uint32_t, f);
    u += 0x7fffu + ((u >> 16) & 1u);   // RNE
    return (uint16_t)(u >> 16);
}

__device__ __forceinline__ void gll16(const void* g, void* l) {
    __builtin_amdgcn_global_load_lds(
        (__attribute__((address_space(1))) void*)g,
        (__attribute__((address_space(3))) void*)l, 16, 0, 0);
}

// ---------------- pre-kernel 1: weight pack + zero slab ----------------
// wpk flat: (((k27*2 + cb)*2 + ct)*64 + lane)*8 + j
//   lane holds A[co = ct*32 + (lane&31)][ci = cb*16 + (lane>>5)*8 + j]
__global__ void pack_weights(const float* __restrict__ w, uint16_t* __restrict__ wpk,
                             uint4* __restrict__ zp) {
    int flat = blockIdx.x * 256 + threadIdx.x;
    if (flat < WPK_U16) {
        int j   = flat & 7;
        int l   = (flat >> 3) & 63;
        int ct  = (flat >> 9) & 1;
        int cb  = (flat >> 10) & 1;
        int k27 = flat >> 11;
        int co = ct * 32 + (l & 31);
        int ci = cb * 16 + ((l >> 5) * 8) + j;
        wpk[flat] = f2bf(w[(co * CIN + ci) * 27 + k27]);
    } else if (flat - WPK_U16 < (int)(ZP_BYTES / 16)) {
        zp[flat - WPK_U16] = make_uint4(0, 0, 0, 0);
    }
}

// ---------------- pre-kernel 2: x -> oct-major padded channel-last bf16 ----------------
__global__ __launch_bounds__(256)
void transpose_x(const float* __restrict__ x, uint16_t* __restrict__ xt) {
    __shared__ uint16_t tile[4 * 66 * 8];   // [oct][sx][j]
    const int yy = blockIdx.x, z = blockIdx.y, b = blockIdx.z;
    const int y = yy - 1;
    const int t = threadIdx.x;
    uint4* dst0 = (uint4*)(xt + ((((size_t)(b * DD + z)) * 4 + 0) * 66 + yy) * (ROW_B_ / 2));
    const size_t oct_stride4 = PLANE_OCT / 16;

    if (y < 0 || y >= DD) {
        for (int i = t; i < 264; i += 256)
            dst0[(i / 66) * oct_stride4 + (i % 66)] = make_uint4(0, 0, 0, 0);
        return;
    }
    const int ci = t >> 3;
    const int xs = (t & 7) * 8;
    const float* src = x + ((((size_t)b * CIN + ci) * DD + z) * DD + y) * DD + xs;
    float4 v0 = *(const float4*)src;
    float4 v1 = *(const float4*)(src + 4);
    float vals[8] = {v0.x, v0.y, v0.z, v0.w, v1.x, v1.y, v1.z, v1.w};
    const int oct = ci >> 3, j = ci & 7;
#pragma unroll
    for (int e = 0; e < 8; ++e)
        tile[(oct * 66 + (xs + e + 1)) * 8 + j] = f2bf(vals[e]);
    if (t < 64) {
        const int o2 = t >> 4, s2 = ((t >> 3) & 1) ? 65 : 0, j2 = t & 7;
        tile[(o2 * 66 + s2) * 8 + j2] = 0;
    }
    __syncthreads();
    const uint4* t4 = (const uint4*)tile;
    for (int i = t; i < 264; i += 256)
        dst0[(i / 66) * oct_stride4 + (i % 66)] = t4[i];
}

// ---------------- main kernel ----------------
// grid (16 yq, 64 z, 2 b) x 256 thr = 4 waves: ct = w&1, xtile = w>>1.
// Wave: 4y x 32x x 32co. Two cb passes; per phase: 9 wf, 18 ds, 36 MFMA.
__global__ __launch_bounds__(256, 4)
void conv_mfma(const uint16_t* __restrict__ xt, const uint16_t* __restrict__ wpk,
               const uint16_t* __restrict__ zp,
               const int* __restrict__ mask, const float* __restrict__ bias,
               float* __restrict__ out) {
    extern __shared__ __align__(16) unsigned char lds[];   // [zr3][oct2][row6][sx66]x16B
    const int yq = blockIdx.x, z = blockIdx.y, b = blockIdx.z;
    const int y0 = yq * 4;
    const int tid = threadIdx.x;
    const int lane = tid & 63;
    const int w = __builtin_amdgcn_readfirstlane(tid >> 6);
    const int ct    = w & 1;
    const int xtile = w >> 1;
    const int u = lane & 31;
    const int h = lane >> 5;
    const int xoff = xtile * 32;

    f32x16 acc[4] = {};   // y = y0 .. y0+3

#pragma unroll
    for (int cbsel = 0; cbsel < 2; ++cbsel) {
        if (cbsel) __syncthreads();   // all reads of previous pass done

        // ---- stage 6 runs (zr x o2) of octs {2*cbsel, 2*cbsel+1}; OOB z -> zero slab ----
        for (int r = w; r < 6; r += 4) {
            const int zr = r >> 1, o2 = r & 1;
            const int oct = cbsel * 2 + o2;
            const int zz = z - 1 + zr;
            const char* g = (zz >= 0 && zz < DD)
                ? (const char*)xt + ((((size_t)(b * DD + zz)) * 4 + oct) * 66 + y0) * ROW_B_
                : (const char*)zp + oct * OCT_B;
            const unsigned l = (unsigned)(zr * SLAB2_B + o2 * OCT_B);
#pragma unroll
            for (int c = 0; c < 6; ++c)
                gll16(g + c * 1024 + lane * 16, &lds[l + (unsigned)c * 1024u]);
            if (lane < 12) gll16(g + 6144 + lane * 16, &lds[l + 6144u]);
        }
        __syncthreads();

#pragma unroll
        for (int zr = 0; zr < 3; ++zr) {
            // 9 weight frags for (zr, cbsel, ct) -> VGPRs (L1/L2-hot)
            bf16x8 wf[9];
#pragma unroll
            for (int q = 0; q < 9; ++q)
                wf[q] = *(const bf16x8*)(wpk
                    + (size_t)(((zr * 9 + q) * 2 + cbsel) * 2 + ct) * 512 + lane * 8);
            const unsigned ob = (unsigned)(zr * SLAB2_B + h * OCT_B)
                              + (unsigned)(xoff + u) * 16u;
#pragma unroll
            for (int t = 0; t < 6; ++t) {
                bf16x8 bf[3];
#pragma unroll
                for (int kx = 0; kx < 3; ++kx)
                    bf[kx] = *(const bf16x8*)&lds[ob + (unsigned)t * ROW_B_ + kx * 16u];
#pragma unroll
                for (int ly = 0; ly < 4; ++ly) {
                    const int ky = t - ly;
                    if (ky >= 0 && ky < 3) {
#pragma unroll
                        for (int kx = 0; kx < 3; ++kx)
                            acc[ly] = __builtin_amdgcn_mfma_f32_32x32x16_bf16(
                                wf[ky * 3 + kx], bf[kx], acc[ly], 0, 0, 0);
                    }
                }
            }
        }
    }

    // ---- epilogue: +bias, x mask, store. C: col = u (x), row = (r&3)+8*(r>>2)+4*h (co) ----
    const size_t mb = (((size_t)b * DD + z) * DD + y0) * DD + xoff + u;
    float m[4];
#pragma unroll
    for (int ly = 0; ly < 4; ++ly) m[ly] = mask[mb + ly * DD] ? 1.0f : 0.0f;
#pragma unroll
    for (int r = 0; r < 16; ++r) {
        const int co = ct * 32 + (r & 3) + 8 * (r >> 2) + 4 * h;
        const float bs = bias[co];
        const size_t o = (((size_t)(b * COUT + co) * DD + z) * DD + y0) * DD + xoff + u;
#pragma unroll
        for (int ly = 0; ly < 4; ++ly)
            out[o + ly * DD] = (acc[ly][r] + bs) * m[ly];
    }
}

// ---------------- fp32 fallback (ws too small) ----------------
#define CI_BLK 16
__global__ __launch_bounds__(256, 2)
void sparse_conv3d_f32(const float* __restrict__ x,
                       const int* __restrict__ mask,
                       const float* __restrict__ weight,
                       const float* __restrict__ bias,
                       float* __restrict__ out) {
    __shared__ float lds[9 * CI_BLK * 66];
    const int y = blockIdx.x, z = blockIdx.y, b = blockIdx.z;
    const int lane = threadIdx.x & 63;
    const int wave = __builtin_amdgcn_readfirstlane(threadIdx.x >> 6);
    float acc[16];
#pragma unroll
    for (int j = 0; j < 16; ++j) acc[j] = 0.0f;
    const int co0 = wave * 16;
    const float* wbase = weight + (size_t)co0 * (CIN * 27);
    for (int cbl = 0; cbl < 2; ++cbl) {
        if (cbl) __syncthreads();
        for (int i = wave; i < 9 * CI_BLK; i += 4) {
            const int r = i >> 4, ci_l = i & 15;
            const int zz = z + (r / 3) - 1, yy = y + (r % 3) - 1;
            const int ci = cbl * CI_BLK + ci_l;
            float v = 0.0f;
            if (zz >= 0 && zz < DD && yy >= 0 && yy < DD)
                v = x[((((size_t)b * CIN + ci) * DD + zz) * DD + yy) * DD + lane];
            float* row = &lds[(size_t)i * 66];
            row[1 + lane] = v;
            if (lane == 0) { row[0] = 0.0f; row[65] = 0.0f; }
        }
        __syncthreads();
        for (int ci_l = 0; ci_l < CI_BLK; ++ci_l) {
            const int ci = cbl * CI_BLK + ci_l;
#pragma unroll
            for (int kz = 0; kz < 3; ++kz) {
#pragma unroll
                for (int ky = 0; ky < 3; ++ky) {
                    const int r = kz * 3 + ky;
                    const float* xrow = &lds[(size_t)(r * CI_BLK + ci_l) * 66 + lane];
                    const float xv0 = xrow[0], xv1 = xrow[1], xv2 = xrow[2];
                    const float* wp = wbase + ci * 27 + kz * 9 + ky * 3;
#pragma unroll
                    for (int j = 0; j < 16; ++j) {
                        acc[j] += wp[(size_t)j * (CIN * 27) + 0] * xv0
                                + wp[(size_t)j * (CIN * 27) + 1] * xv1
                                + wp[(size_t)j * (CIN * 27) + 2] * xv2;
                    }
                }
            }
        }
    }
    const float m = mask[(((size_t)b * DD + z) * DD + y) * DD + lane] ? 1.0f : 0.0f;
#pragma unroll
    for (int j = 0; j < 16; ++j) {
        const int co = co0 + j;
        out[((((size_t)b * COUT + co) * DD + z) * DD + y) * DD + lane] = (acc[j] + bias[co]) * m;
    }
}
#undef CI_BLK

extern "C" void kernel_launch(void* const* d_in, const int* in_sizes, int n_in,
                              void* d_out, int out_size, void* d_ws, size_t ws_size,
                              hipStream_t stream) {
    const float* x    = (const float*)d_in[0];
    const int*   mask = (const int*)d_in[1];
    const float* w    = (const float*)d_in[2];
    const float* bias = (const float*)d_in[3];
    float*       out  = (float*)d_out;

    if (ws_size < WS_NEEDED) {
        sparse_conv3d_f32<<<dim3(DD, DD, 2), 256, 0, stream>>>(x, mask, w, bias, out);
        return;
    }

    uint16_t* xt  = (uint16_t*)d_ws;
    uint16_t* wpk = (uint16_t*)((char*)d_ws + XT_BYTES);
    uint16_t* zp  = (uint16_t*)((char*)d_ws + XT_BYTES + WPK_BYTES);

    pack_weights<<<(WPK_U16 + (int)(ZP_BYTES / 16) + 255) / 256, 256, 0, stream>>>(w, wpk, (uint4*)zp);
    transpose_x<<<dim3(66, DD, 2), 256, 0, stream>>>(x, xt);
    conv_mfma<<<dim3(16, DD, 2), 256, CONV_LDS, stream>>>(xt, wpk, zp, mask, bias, out);
}

// Round 14
// 89.689 us; speedup vs baseline: 1.1052x; 1.0582x over previous
//
#include <hip/hip_runtime.h>
#include <stdint.h>

// SparseConv3d bf16-MFMA implicit GEMM. B=2, Cin=32, Cout=64, D=64, K=3.
// Round 14: r11 (best, 80us) + weight ping-pong ONLY.
//   r11 shape: 512-thr, 8 waves (ct x xtile x wy), y-quad tile, 76KB LDS
//   (3 slabs x 4 octs, conflict-free oct-major), 2 blocks/CU = 16 waves/CU.
//   NEW: wf for phase p+1 prefetched during phase p's MFMA burst (wfA/wfB
//   ping-pong) -- kills the ~300cyc L2 stall at each of the 6 phase heads
//   (wpk = 110KB >> 32KB L1, so wf loads are L2 hits; r11's VGPR=48 shows
//   the compiler allocated no prefetch buffer on its own).
//   Register budget: acc 32 (AGPR) + wfA/B 72 + bf 12 + addr ~ 125 <= 128;
//   bf double-buffer dropped (ds 120cyc << L2 300cyc). launch_bounds(512,4).
// xt: [b][z][oct][yy(66 pad)][sx(66 pad)] 16B units; zero pad rows/slots.

#define DD 64
#define CIN 32
#define COUT 64

typedef __bf16 bf16x8 __attribute__((ext_vector_type(8)));
typedef float f32x16 __attribute__((ext_vector_type(16)));

#define ROW_B_    1056u                                 // 66 sx * 16B
#define OCT_B     6336u                                 // 6 rows * 1056
#define SLAB_B    25344u                                // 4 octs (one z-plane)
#define PLANE_OCT (66u * ROW_B_)                        // one oct, full plane
#define XT_BYTES  ((size_t)2 * 64 * 4 * 66 * ROW_B_)    // 35,684,352
#define WPK_U16   (27 * 2 * 2 * 64 * 8)                 // 55,296
#define WPK_BYTES ((size_t)WPK_U16 * 2)
#define ZP_BYTES  ((size_t)SLAB_B)
#define WS_NEEDED (XT_BYTES + WPK_BYTES + ZP_BYTES)
#define CONV_LDS  (3 * 25344)                           // 76,032 B

__device__ __forceinline__ uint16_t f2bf(float f) {
    uint32_t u = __builtin_bit_cast(uint32_t, f);
    u += 0x7fffu + ((u >> 16) & 1u);   // RNE
    return (uint16_t)(u >> 16);
}

__device__ __forceinline__ void gll16(const void* g, void* l) {
    __builtin_amdgcn_global_load_lds(
        (__attribute__((address_space(1))) void*)g,
        (__attribute__((address_space(3))) void*)l, 16, 0, 0);
}

// ---------------- pre-kernel 1: weight pack + zero slab ----------------
// wpk flat: (((k27*2 + cb)*2 + ct)*64 + lane)*8 + j
//   lane holds A[co = ct*32 + (lane&31)][ci = cb*16 + (lane>>5)*8 + j]
__global__ void pack_weights(const float* __restrict__ w, uint16_t* __restrict__ wpk,
                             uint4* __restrict__ zp) {
    int flat = blockIdx.x * 256 + threadIdx.x;
    if (flat < WPK_U16) {
        int j   = flat & 7;
        int l   = (flat >> 3) & 63;
        int ct  = (flat >> 9) & 1;
        int cb  = (flat >> 10) & 1;
        int k27 = flat >> 11;
        int co = ct * 32 + (l & 31);
        int ci = cb * 16 + ((l >> 5) * 8) + j;
        wpk[flat] = f2bf(w[(co * CIN + ci) * 27 + k27]);
    } else if (flat - WPK_U16 < (int)(ZP_BYTES / 16)) {
        zp[flat - WPK_U16] = make_uint4(0, 0, 0, 0);
    }
}

// ---------------- pre-kernel 2: x -> oct-major padded channel-last bf16 ----------------
__global__ __launch_bounds__(256)
void transpose_x(const float* __restrict__ x, uint16_t* __restrict__ xt) {
    __shared__ uint16_t tile[4 * 66 * 8];   // [oct][sx][j]
    const int yy = blockIdx.x, z = blockIdx.y, b = blockIdx.z;
    const int y = yy - 1;
    const int t = threadIdx.x;
    uint4* dst0 = (uint4*)(xt + ((((size_t)(b * DD + z)) * 4 + 0) * 66 + yy) * (ROW_B_ / 2));
    const size_t oct_stride4 = PLANE_OCT / 16;

    if (y < 0 || y >= DD) {
        for (int i = t; i < 264; i += 256)
            dst0[(i / 66) * oct_stride4 + (i % 66)] = make_uint4(0, 0, 0, 0);
        return;
    }
    const int ci = t >> 3;
    const int xs = (t & 7) * 8;
    const float* src = x + ((((size_t)b * CIN + ci) * DD + z) * DD + y) * DD + xs;
    float4 v0 = *(const float4*)src;
    float4 v1 = *(const float4*)(src + 4);
    float vals[8] = {v0.x, v0.y, v0.z, v0.w, v1.x, v1.y, v1.z, v1.w};
    const int oct = ci >> 3, j = ci & 7;
#pragma unroll
    for (int e = 0; e < 8; ++e)
        tile[(oct * 66 + (xs + e + 1)) * 8 + j] = f2bf(vals[e]);
    if (t < 64) {
        const int o2 = t >> 4, s2 = ((t >> 3) & 1) ? 65 : 0, j2 = t & 7;
        tile[(o2 * 66 + s2) * 8 + j2] = 0;
    }
    __syncthreads();
    const uint4* t4 = (const uint4*)tile;
    for (int i = t; i < 264; i += 256)
        dst0[(i / 66) * oct_stride4 + (i % 66)] = t4[i];
}

// ---------------- main kernel ----------------
// grid (16 yq, 64 z, 2 b) x 512 thr = 8 waves: ct = w&1, xtile = (w>>1)&1, wy = w>>2.
// Wave: 2y x 32x x 32co. Phase (zr,cb): 9 wf (ping-pong prefetched) : 12 ds : 18 MFMA.
__global__ __launch_bounds__(512, 4)
void conv_mfma(const uint16_t* __restrict__ xt, const uint16_t* __restrict__ wpk,
               const uint16_t* __restrict__ zp,
               const int* __restrict__ mask, const float* __restrict__ bias,
               float* __restrict__ out) {
    extern __shared__ __align__(16) unsigned char lds[];   // [zr3][oct4][row6][sx66]x16B
    const int yq = blockIdx.x, z = blockIdx.y, b = blockIdx.z;
    const int y0 = yq * 4;
    const int tid = threadIdx.x;
    const int lane = tid & 63;
    const int w = __builtin_amdgcn_readfirstlane(tid >> 6);
    const int ct    = w & 1;
    const int xtile = (w >> 1) & 1;
    const int wy    = w >> 2;
    const int u = lane & 31;
    const int h = lane >> 5;
    const int xoff = xtile * 32;

    // ---- stage 12 runs (zr x oct), each 6336 B contiguous; OOB z -> zero slab ----
    for (int r = w; r < 12; r += 8) {
        const int zr = r >> 2, oct = r & 3;
        const int zz = z - 1 + zr;
        const char* g = (zz >= 0 && zz < DD)
            ? (const char*)xt + ((((size_t)(b * DD + zz)) * 4 + oct) * 66 + y0) * ROW_B_
            : (const char*)zp + oct * OCT_B;
        const unsigned l = (unsigned)(zr * SLAB_B + oct * OCT_B);
#pragma unroll
        for (int c = 0; c < 6; ++c)
            gll16(g + c * 1024 + lane * 16, &lds[l + (unsigned)c * 1024u]);
        if (lane < 12) gll16(g + 6144 + lane * 16, &lds[l + 6144u]);
    }

    bf16x8 wfA[9], wfB[9];
#define LOAD_WF(DST, zr_, cb_)                                                     \
    _Pragma("unroll") for (int q = 0; q < 9; ++q)                                  \
        DST[q] = *(const bf16x8*)(wpk                                              \
            + (size_t)((((zr_) * 9 + q) * 2 + (cb_)) * 2 + ct) * 512 + lane * 8);

    LOAD_WF(wfA, 0, 0)          // phase-0 weights in flight during barrier wait
    __syncthreads();

    f32x16 acc0 = {}, acc1 = {};   // y = y0+2wy, y0+2wy+1

#define PHASE(zr_, cb_, WFC, WFN, pzr, pcb, DOPRE)                                 \
    {   if (DOPRE) { LOAD_WF(WFN, pzr, pcb) }                                      \
        const unsigned ob = (unsigned)((zr_) * SLAB_B + ((cb_) * 2 + h) * OCT_B)   \
                          + (unsigned)(xoff + u) * 16u;                            \
        _Pragma("unroll") for (int t = 0; t < 4; ++t) {                            \
            bf16x8 bf[3];                                                          \
            _Pragma("unroll") for (int kx = 0; kx < 3; ++kx)                       \
                bf[kx] = *(const bf16x8*)&lds[ob + (unsigned)(2 * wy + t) * ROW_B_ \
                                              + kx * 16u];                         \
            _Pragma("unroll") for (int kx = 0; kx < 3; ++kx) {                     \
                if (t <= 2)   /* ly=0, ky=t   */                                   \
                    acc0 = __builtin_amdgcn_mfma_f32_32x32x16_bf16(                \
                        WFC[t * 3 + kx], bf[kx], acc0, 0, 0, 0);                   \
                if (t >= 1)   /* ly=1, ky=t-1 */                                   \
                    acc1 = __builtin_amdgcn_mfma_f32_32x32x16_bf16(                \
                        WFC[(t - 1) * 3 + kx], bf[kx], acc1, 0, 0, 0);             \
            }                                                                      \
        }                                                                          \
    }

    PHASE(0, 0, wfA, wfB, 0, 1, 1)
    PHASE(0, 1, wfB, wfA, 1, 0, 1)
    PHASE(1, 0, wfA, wfB, 1, 1, 1)
    PHASE(1, 1, wfB, wfA, 2, 0, 1)
    PHASE(2, 0, wfA, wfB, 2, 1, 1)
    PHASE(2, 1, wfB, wfA, 0, 0, 0)
#undef PHASE
#undef LOAD_WF

    // ---- epilogue: +bias, x mask, store. C: col = u (x), row = (r&3)+8*(r>>2)+4*h (co) ----
    const int ya = y0 + 2 * wy;
    const size_t mb = (((size_t)b * DD + z) * DD + ya) * DD + xoff + u;
    const float m0 = mask[mb]      ? 1.0f : 0.0f;
    const float m1 = mask[mb + DD] ? 1.0f : 0.0f;
#pragma unroll
    for (int r = 0; r < 16; ++r) {
        const int co = ct * 32 + (r & 3) + 8 * (r >> 2) + 4 * h;
        const float bs = bias[co];
        const size_t o = (((size_t)(b * COUT + co) * DD + z) * DD + ya) * DD + xoff + u;
        out[o]      = (acc0[r] + bs) * m0;
        out[o + DD] = (acc1[r] + bs) * m1;
    }
}

// ---------------- fp32 fallback (ws too small) ----------------
#define CI_BLK 16
__global__ __launch_bounds__(256, 2)
void sparse_conv3d_f32(const float* __restrict__ x,
                       const int* __restrict__ mask,
                       const float* __restrict__ weight,
                       const float* __restrict__ bias,
                       float* __restrict__ out) {
    __shared__ float lds[9 * CI_BLK * 66];
    const int y = blockIdx.x, z = blockIdx.y, b = blockIdx.z;
    const int lane = threadIdx.x & 63;
    const int wave = __builtin_amdgcn_readfirstlane(threadIdx.x >> 6);
    float acc[16];
#pragma unroll
    for (int j = 0; j < 16; ++j) acc[j] = 0.0f;
    const int co0 = wave * 16;
    const float* wbase = weight + (size_t)co0 * (CIN * 27);
    for (int cbl = 0; cbl < 2; ++cbl) {
        if (cbl) __syncthreads();
        for (int i = wave; i < 9 * CI_BLK; i += 4) {
            const int r = i >> 4, ci_l = i & 15;
            const int zz = z + (r / 3) - 1, yy = y + (r % 3) - 1;
            const int ci = cbl * CI_BLK + ci_l;
            float v = 0.0f;
            if (zz >= 0 && zz < DD && yy >= 0 && yy < DD)
                v = x[((((size_t)b * CIN + ci) * DD + zz) * DD + yy) * DD + lane];
            float* row = &lds[(size_t)i * 66];
            row[1 + lane] = v;
            if (lane == 0) { row[0] = 0.0f; row[65] = 0.0f; }
        }
        __syncthreads();
        for (int ci_l = 0; ci_l < CI_BLK; ++ci_l) {
            const int ci = cbl * CI_BLK + ci_l;
#pragma unroll
            for (int kz = 0; kz < 3; ++kz) {
#pragma unroll
                for (int ky = 0; ky < 3; ++ky) {
                    const int r = kz * 3 + ky;
                    const float* xrow = &lds[(size_t)(r * CI_BLK + ci_l) * 66 + lane];
                    const float xv0 = xrow[0], xv1 = xrow[1], xv2 = xrow[2];
                    const float* wp = wbase + ci * 27 + kz * 9 + ky * 3;
#pragma unroll
                    for (int j = 0; j < 16; ++j) {
                        acc[j] += wp[(size_t)j * (CIN * 27) + 0] * xv0
                                + wp[(size_t)j * (CIN * 27) + 1] * xv1
                                + wp[(size_t)j * (CIN * 27) + 2] * xv2;
                    }
                }
            }
        }
    }
    const float m = mask[(((size_t)b * DD + z) * DD + y) * DD + lane] ? 1.0f : 0.0f;
#pragma unroll
    for (int j = 0; j < 16; ++j) {
        const int co = co0 + j;
        out[((((size_t)b * COUT + co) * DD + z) * DD + y) * DD + lane] = (acc[j] + bias[co]) * m;
    }
}
#undef CI_BLK

extern "C" void kernel_launch(void* const* d_in, const int* in_sizes, int n_in,
                              void* d_out, int out_size, void* d_ws, size_t ws_size,
                              hipStream_t stream) {
    const float* x    = (const float*)d_in[0];
    const int*   mask = (const int*)d_in[1];
    const float* w    = (const float*)d_in[2];
    const float* bias = (const float*)d_in[3];
    float*       out  = (float*)d_out;

    if (ws_size < WS_NEEDED) {
        sparse_conv3d_f32<<<dim3(DD, DD, 2), 256, 0, stream>>>(x, mask, w, bias, out);
        return;
    }

    uint16_t* xt  = (uint16_t*)d_ws;
    uint16_t* wpk = (uint16_t*)((char*)d_ws + XT_BYTES);
    uint16_t* zp  = (uint16_t*)((char*)d_ws + XT_BYTES + WPK_BYTES);

    pack_weights<<<(WPK_U16 + (int)(ZP_BYTES / 16) + 255) / 256, 256, 0, stream>>>(w, wpk, (uint4*)zp);
    transpose_x<<<dim3(66, DD, 2), 256, 0, stream>>>(x, xt);
    conv_mfma<<<dim3(16, DD, 2), 512, CONV_LDS, stream>>>(xt, wpk, zp, mask, bias, out);
}